// Round 1
// baseline (81.700 us; speedup 1.0000x reference)
//
#include <hip/hip_runtime.h>
#include <math.h>

#define DIM  4096
#define BLK  256            // 4 waves; 16 amplitudes (v2f) per thread; 1 wave/SIMD
#define NPAR 144

typedef float v2f __attribute__((ext_vector_type(2)));

// ---------------------------------------------------------------------------
// R13 = 4 register bits per thread (16 amps), 256 threads, 8 epochs/layer.
// 12 canonical bits per phase: 4 register bits, 2 wave bits (tid 6..7),
// 6 lane bits (tid 0..5). Window slides 3 bits/epoch -> 8 epochs/layer,
// 23 restages total (vs 35 at 3 reg bits): LDS traffic -34%.
// Wave-pinned runs -> wave-local restages (no barrier; same-wave LDS ops are
// serviced in program order, R7-validated). Transition windows share >=1 reg
// bit -> full b128 stash AND unstash. Angles in lane-distributed VGPRs via
// v_readlane. Per-thread LDS addresses cached once (maps repeat mod 8,
// constexpr-verified).
// Canonical bit b <-> python wire w = 11-b (validated R1-R12 convention).
// chain1 (group1, angle 12+i): CRX(control=bit i, target=bit i-1 mod 12),
//   i = 0..11 in order.
// chain2 (group3, angle 36+i): (0,1),(11,0),(10,11),(9,10),...,(1,2).
// RY1 angle = 11-b; RY2 angle = 24 + (11-b).
// ---------------------------------------------------------------------------
struct Ph { int reg[4]; int wav[2]; };
struct TMap { unsigned pk[8]; unsigned short so[16]; unsigned short rn[16]; };

constexpr int REGS4[8][4] = {
  {11,0,1,2},{2,3,4,5},{5,6,7,8},{8,9,10,11},
  {10,11,0,1},{7,8,9,10},{4,5,6,7},{1,2,3,4}};
constexpr int PINS[8][2] = {
  {9,10},{9,10},{9,10},{2,3},{2,3},{2,3},{2,3},{9,10}};

constexpr Ph phaseAt(int i) {         // i = 0..24; 0 = pseudo (== epoch 0)
  Ph p = {};
  int e = (i == 0) ? 0 : (i - 1) % 8;
  for (int j = 0; j < 4; ++j) p.reg[j] = REGS4[e][j];
  p.wav[0] = PINS[e][0]; p.wav[1] = PINS[e][1];
  return p;
}
constexpr bool inArr(const int* a, int n, int b) {
  for (int i = 0; i < n; ++i) if (a[i] == b) return true;
  return false;
}
constexpr int idxOf4(const int* a, int v) {
  for (int j = 0; j < 4; ++j) if (a[j] == v) return j;
  return -1;
}
constexpr bool isLoc(int t) {
  Ph a = phaseAt(t), b = phaseAt(t + 1);
  return a.wav[0]==b.wav[0] && a.wav[1]==b.wav[1];
}
constexpr int bufIdx(int t) {
  int k = 0;
  for (int u = 0; u <= t; ++u) if (!isLoc(u)) ++k;
  return (k + 1) & 1;
}
constexpr int sharedBit(Ph o, Ph n) {
  for (int j = 0; j < 4; ++j) if (inArr(n.reg, 4, o.reg[j])) return o.reg[j];
  return -1;
}

struct BuildOut { TMap m; int js, jn; bool ok; };

// GF(2)-linear canonical->slot map (R7-validated construction, widened).
// Row 0 = shared reg bit (b128 pairing both sides). Rows 1..3 = lane bits
// common to both phases (bank-conflict-free b128: byte bits 4..6). Local:
// wave bits -> rows 10..11 (private 8 KB/wave region).
constexpr BuildOut buildT(Ph o, Ph n, bool local) {
  BuildOut R = {};
  R.ok = true;
  int s = sharedBit(o, n);
  if (s < 0) { R.ok = false; return R; }
  R.js = idxOf4(o.reg, s);
  R.jn = idxOf4(n.reg, s);
  if (R.js < 0 || R.jn < 0) { R.ok = false; return R; }
  bool lo[12] = {}, ln[12] = {};
  for (int b = 0; b < 12; ++b) {
    lo[b] = !inArr(o.reg,4,b) && !inArr(o.wav,2,b);
    ln[b] = !inArr(n.reg,4,b) && !inArr(n.wav,2,b);
  }
  int col[12] = {};
  bool uo[12] = {}, un[12] = {}, consumed[12] = {};
  col[s] = 1; consumed[s] = true;
  int row = 1;
  for (int b = 0; b < 12 && row < 4; ++b)
    if (lo[b] && ln[b] && !consumed[b]) { col[b] = 1 << row; uo[b]=un[b]=true; consumed[b]=true; ++row; }
  while (row < 4) {
    int a = -1, c = -1;
    for (int b = 0; b < 12; ++b) if (lo[b] && !uo[b] && !consumed[b]) { a = b; break; }
    for (int b = 0; b < 12; ++b) if (ln[b] && !un[b] && !consumed[b] && b != a) { c = b; break; }
    if (a < 0 || c < 0) { R.ok = false; return R; }
    col[a] |= 1 << row; col[c] |= 1 << row;
    uo[a]=true; un[c]=true; consumed[c]=true;
    ++row;
  }
  if (local) {
    for (int i = 0; i < 2; ++i) {
      if (consumed[o.wav[i]]) { R.ok = false; return R; }
      col[o.wav[i]] |= 1 << (10 + i);
      consumed[o.wav[i]] = true;
    }
    int rr = 4;
    for (int b = 0; b < 12; ++b) if (!consumed[b]) { col[b] |= 1 << rr; ++rr; }
    if (rr != 10) { R.ok = false; return R; }
  } else {
    int rr = 4;
    for (int b = 0; b < 12; ++b) if (!consumed[b]) { col[b] |= 1 << rr; ++rr; }
    if (rr != 12) { R.ok = false; return R; }
  }
  {                                     // rank-12 invertibility over GF(2)
    int pv[12] = {}, pb[12] = {};
    int nr = 0;
    for (int b = 0; b < 12; ++b) {
      int v = col[b];
      for (int k = 0; k < nr; ++k) if (v & pb[k]) v ^= pv[k];
      if (v) { pb[nr] = v & (-v); pv[nr] = v; ++nr; }
    }
    if (nr != 12) { R.ok = false; return R; }
  }
  int Lo[6] = {}, Ln6[6] = {};
  int i0 = 0, i1 = 0;
  for (int b = 0; b < 12; ++b) { if (lo[b]) Lo[i0++] = b; if (ln[b]) Ln6[i1++] = b; }
  if (i0 != 6 || i1 != 6) { R.ok = false; return R; }
  for (int i = 0; i < 8; ++i) {
    unsigned po = (i < 6) ? (unsigned)col[Lo[i]] : (unsigned)col[o.wav[i-6]];
    unsigned pn = (i < 6) ? (unsigned)col[Ln6[i]] : (unsigned)col[n.wav[i-6]];
    R.m.pk[i] = po | (pn << 16);
  }
  for (int r = 0; r < 16; ++r) {
    int a = 0, c = 0;
    for (int j = 0; j < 4; ++j)
      if ((r >> j) & 1) { a ^= col[o.reg[j]]; c ^= col[n.reg[j]]; }
    R.m.so[r] = (unsigned short)(a * 8);
    R.m.rn[r] = (unsigned short)(c * 8);
  }
  return R;
}

constexpr bool mapsEqual(const TMap& a, const TMap& b) {
  for (int i = 0; i < 8; ++i) if (a.pk[i] != b.pk[i]) return false;
  for (int r = 0; r < 16; ++r)
    if (a.so[r] != b.so[r] || a.rn[r] != b.rn[r]) return false;
  return true;
}

struct AllT { TMap t[24]; bool loc[24]; int buf[24]; int js[24]; int jn[24]; bool ok; };
constexpr AllT buildAll() {
  AllT A = {};
  A.ok = true;
  for (int t = 0; t < 24; ++t) {
    BuildOut b = buildT(phaseAt(t), phaseAt(t + 1), isLoc(t));
    A.t[t] = b.m;
    A.ok = A.ok && b.ok;
    A.loc[t] = isLoc(t);
    A.buf[t] = bufIdx(t);
    A.js[t] = b.js;
    A.jn[t] = b.jn;
  }
  // transition classes repeat with period 8 (enables cached per-thread addrs)
  for (int t = 9; t < 24; ++t)
    A.ok = A.ok && mapsEqual(A.t[t], A.t[t-8]) && A.loc[t] == A.loc[t-8]
         && A.buf[t] == A.buf[t-8] && A.js[t] == A.js[t-8] && A.jn[t] == A.jn[t-8];
  // exactly 2 barrier restages per layer, at epoch 2->3 and 6->7
  {
    int ng = 0;
    for (int t = 1; t < 24; ++t) if (!A.loc[t]) ++ng;
    A.ok = A.ok && (ng == 6);
    for (int t = 1; t < 24; ++t) {
      bool expectGlob = (((t - 1) % 8) == 2) || (((t - 1) % 8) == 6);
      A.ok = A.ok && (A.loc[t] == !expectGlob);
    }
  }
  return A;
}
constexpr AllT AT = buildAll();
static_assert(AT.ok, "slot-map construction failed");

// ---------------- angle fetch via v_readlane --------------------------------
__device__ __forceinline__ float rlf(float v, int l) {
  return __int_as_float(__builtin_amdgcn_readlane(__float_as_int(v), l));
}
template<int AO>
__device__ __forceinline__ v2f angAt(const float (&ct)[3], const float (&st)[3]) {
  v2f a;
  a.x = rlf(ct[AO >> 6], AO & 63);
  a.y = rlf(st[AO >> 6], AO & 63);
  return a;
}

// ---------------- gates on the 16-amplitude register file -------------------
template<int J>
__device__ __forceinline__ void ry16(v2f (&z)[16], v2f a) {
  const float c = a.x, s = a.y;
  #pragma unroll
  for (int p = 0; p < 8; ++p) {
    const int r0 = ((p & ~((1 << J) - 1)) << 1) | (p & ((1 << J) - 1));
    const int r1 = r0 | (1 << J);
    v2f u = z[r0], v = z[r1];
    z[r0] = c * u - s * v;
    z[r1] = s * u + c * v;
  }
}
// CRX, off-diagonal -i*s (validated R1-R12)
template<int JC, int JT>
__device__ __forceinline__ void crx16(v2f (&z)[16], v2f a) {
  const float c = a.x, s = a.y;
  constexpr int MC = 1 << JC, MT = 1 << JT;
  constexpr int mlo = MC < MT ? MC : MT;
  constexpr int mhi = MC < MT ? MT : MC;
  #pragma unroll
  for (int p = 0; p < 4; ++p) {
    int q = ((p & ~(mlo - 1)) << 1) | (p & (mlo - 1));
    q = ((q & ~(mhi - 1)) << 1) | (q & (mhi - 1));
    const int r0 = q | MC, r1 = r0 | MT;
    v2f u = z[r0], v = z[r1];
    v2f n0, n1;
    n0.x = c * u.x + s * v.y;
    n0.y = c * u.y - s * v.x;
    n1.x = c * v.x + s * u.y;
    n1.y = c * v.y - s * u.x;
    z[r0] = n0; z[r1] = n1;
  }
}

// Epoch gate lists. Slot j of epoch e <-> canonical bit REGS4[e][j].
// RYs first, then chain CRX links in circuit order.
template<int E, int L>
__device__ __forceinline__ void gates(v2f (&z)[16], const float (&ct)[3], const float (&st)[3]) {
#define A(k) (angAt<48 * L + (k)>(ct, st))
  if constexpr (E == 0)      { ry16<0>(z,A(0));  ry16<1>(z,A(11)); ry16<2>(z,A(10)); ry16<3>(z,A(9));
                               crx16<1,0>(z,A(12)); crx16<2,1>(z,A(13)); crx16<3,2>(z,A(14)); }
  else if constexpr (E == 1) { ry16<1>(z,A(8));  ry16<2>(z,A(7));  ry16<3>(z,A(6));
                               crx16<1,0>(z,A(15)); crx16<2,1>(z,A(16)); crx16<3,2>(z,A(17)); }
  else if constexpr (E == 2) { ry16<1>(z,A(5));  ry16<2>(z,A(4));  ry16<3>(z,A(3));
                               crx16<1,0>(z,A(18)); crx16<2,1>(z,A(19)); crx16<3,2>(z,A(20)); }
  else if constexpr (E == 3) { ry16<1>(z,A(2));  ry16<2>(z,A(1));
                               crx16<1,0>(z,A(21)); crx16<2,1>(z,A(22)); crx16<3,2>(z,A(23)); }
  else if constexpr (E == 4) { ry16<0>(z,A(25)); ry16<1>(z,A(24)); ry16<2>(z,A(35)); ry16<3>(z,A(34));
                               crx16<2,3>(z,A(36)); crx16<1,2>(z,A(37)); crx16<0,1>(z,A(38)); }
  else if constexpr (E == 5) { ry16<0>(z,A(28)); ry16<1>(z,A(27)); ry16<2>(z,A(26));
                               crx16<2,3>(z,A(39)); crx16<1,2>(z,A(40)); crx16<0,1>(z,A(41)); }
  else if constexpr (E == 6) { ry16<0>(z,A(31)); ry16<1>(z,A(30)); ry16<2>(z,A(29));
                               crx16<2,3>(z,A(42)); crx16<1,2>(z,A(43)); crx16<0,1>(z,A(44)); }
  else                       { ry16<1>(z,A(33)); ry16<2>(z,A(32));
                               crx16<2,3>(z,A(45)); crx16<1,2>(z,A(46)); crx16<0,1>(z,A(47)); }
#undef A
}

template<int T>
__device__ __forceinline__ void restage(v2f (&z)[16],
                                        const unsigned (&bo)[8], const unsigned (&bn)[8],
                                        char* Lb, char* C0, char* C1) {
  constexpr int K = (T - 1) & 7;        // maps repeat mod 8 (constexpr-checked)
  constexpr bool LOC = AT.loc[T];
  constexpr int JS = AT.js[T], JN = AT.jn[T];
  char* buf = LOC ? Lb : (AT.buf[T] ? C1 : C0);
  const unsigned o = bo[K], n_ = bn[K];
  // stash: 8 x ds_write_b128, pairing regs over the shared bit (slot bit 0)
  #pragma unroll
  for (int r = 0; r < 16; ++r) {
    if (r & (1 << JS)) continue;
    v2f z0 = z[r], z1 = z[r | (1 << JS)];
    float4 w; w.x = z0.x; w.y = z0.y; w.z = z1.x; w.w = z1.y;
    *(float4*)(buf + (o ^ AT.t[T].so[r])) = w;
  }
  if (LOC) {
    // same-wave LDS ops are serviced in program order (R7-validated):
    // reads queue behind writes — only a compiler fence needed.
    asm volatile("" ::: "memory");
  } else {
    __syncthreads();
  }
  // unstash: 8 x ds_read_b128
  #pragma unroll
  for (int r = 0; r < 16; ++r) {
    if (r & (1 << JN)) continue;
    float4 w = *(const float4*)(buf + (n_ ^ AT.t[T].rn[r]));
    v2f z0, z1;
    z0.x = w.x; z0.y = w.y;
    z1.x = w.z; z1.y = w.w;
    z[r] = z0;
    z[r | (1 << JN)] = z1;
  }
}

template<int L>
__device__ __forceinline__ void layer(v2f (&z)[16],
                                      const unsigned (&bo)[8], const unsigned (&bn)[8],
                                      const float (&ct)[3], const float (&st)[3],
                                      char* Lb, char* C0, char* C1) {
  gates<0, L>(z, ct, st);  restage<8*L + 1>(z, bo, bn, Lb, C0, C1);
  gates<1, L>(z, ct, st);  restage<8*L + 2>(z, bo, bn, Lb, C0, C1);
  gates<2, L>(z, ct, st);  restage<8*L + 3>(z, bo, bn, Lb, C0, C1);
  gates<3, L>(z, ct, st);  restage<8*L + 4>(z, bo, bn, Lb, C0, C1);
  gates<4, L>(z, ct, st);  restage<8*L + 5>(z, bo, bn, Lb, C0, C1);
  gates<5, L>(z, ct, st);  restage<8*L + 6>(z, bo, bn, Lb, C0, C1);
  gates<6, L>(z, ct, st);  restage<8*L + 7>(z, bo, bn, Lb, C0, C1);
  gates<7, L>(z, ct, st);
  if constexpr (L < 2) restage<8*L + 8>(z, bo, bn, Lb, C0, C1);
}

__global__ __launch_bounds__(BLK) void ansatz_kernel(
    const float* __restrict__ sre, const float* __restrict__ sim,
    const float* __restrict__ params, float* __restrict__ out) {

  __shared__ alignas(16) v2f C0s[DIM], C1s[DIM], Ls[DIM];   // 3 x 32 KB

  const int b = blockIdx.x, tid = threadIdx.x;
  char* C0 = (char*)C0s;
  char* C1 = (char*)C1s;
  char* Lb = (char*)Ls;

  // ---- per-wave angle table in lane-distributed VGPRs (no LDS, no barrier)
  float ct[3], st[3];
  {
    const int lane = tid & 63;
    #pragma unroll
    for (int j = 0; j < 3; ++j) {
      int idx = lane + 64 * j;
      int ci = (idx < NPAR) ? idx : 0;
      float th = params[(size_t)b * NPAR + ci];
      sincosf(0.5f * th, &st[j], &ct[j]);
    }
  }

  // ---- cached per-thread restage addresses (maps repeat mod 8) ----
  unsigned bo[8], bn[8];
  #pragma unroll
  for (int k = 0; k < 8; ++k) {
    unsigned acc = 0;
    #pragma unroll
    for (int i = 0; i < 8; ++i)
      acc ^= (unsigned)(-((tid >> i) & 1)) & AT.t[k + 1].pk[i];
    bo[k] = (acc & 0xfffu) << 3;
    bn[k] = ((acc >> 16) & 0xfffu) << 3;
  }

  // ---- init: direct gather in epoch-0 layout ----
  // epoch 0: reg slots {11,0,1,2} (r bit0<->amp bit11, r bits1..3<->amp bits0..2);
  // lanes tid0..5 -> amp bits 3..8; waves tid6,7 -> amp bits 9,10.
  // => base = tid*8, fully coalesced float4 loads.
  v2f z[16];
  {
    const float4* pr = (const float4*)(sre + (size_t)b * DIM + (size_t)tid * 8);
    const float4* pi = (const float4*)(sim + (size_t)b * DIM + (size_t)tid * 8);
    float4 f0 = pr[0], f1 = pr[1], f2 = pr[512], f3 = pr[513];  // +512 f4 = bit 11
    float4 g0 = pi[0], g1 = pi[1], g2 = pi[512], g3 = pi[513];
    z[0].x  = f0.x; z[0].y  = g0.x;  z[2].x  = f0.y; z[2].y  = g0.y;
    z[4].x  = f0.z; z[4].y  = g0.z;  z[6].x  = f0.w; z[6].y  = g0.w;
    z[8].x  = f1.x; z[8].y  = g1.x;  z[10].x = f1.y; z[10].y = g1.y;
    z[12].x = f1.z; z[12].y = g1.z;  z[14].x = f1.w; z[14].y = g1.w;
    z[1].x  = f2.x; z[1].y  = g2.x;  z[3].x  = f2.y; z[3].y  = g2.y;
    z[5].x  = f2.z; z[5].y  = g2.z;  z[7].x  = f2.w; z[7].y  = g2.w;
    z[9].x  = f3.x; z[9].y  = g3.x;  z[11].x = f3.y; z[11].y = g3.y;
    z[13].x = f3.z; z[13].y = g3.z;  z[15].x = f3.w; z[15].y = g3.w;
  }

  layer<0>(z, bo, bn, ct, st, Lb, C0, C1);
  layer<1>(z, bo, bn, ct, st, Lb, C0, C1);
  layer<2>(z, bo, bn, ct, st, Lb, C0, C1);

  // ---- final: direct scatter store from epoch-7 layout ----
  // epoch 7: reg slots {1,2,3,4} (amp = base + 2*r); lanes tid0..5 -> amp bits
  // {0,5,6,7,8,11}; waves tid6,7 -> amp bits 9,10.
  {
    int base = (tid & 1) | ((tid & 2) << 4) | ((tid & 4) << 4)
             | ((tid & 8) << 4) | ((tid & 16) << 4) | ((tid & 32) << 6)
             | ((tid & 64) << 3) | ((tid & 128) << 3);
    v2f* o2 = (v2f*)out + (size_t)b * DIM + base;
    #pragma unroll
    for (int r = 0; r < 16; ++r)
      o2[2 * r] = z[r];
  }
}

extern "C" void kernel_launch(void* const* d_in, const int* in_sizes, int n_in,
                              void* d_out, int out_size, void* d_ws, size_t ws_size,
                              hipStream_t stream) {
  const float* sre    = (const float*)d_in[0];
  const float* sim    = (const float*)d_in[1];
  const float* params = (const float*)d_in[2];
  float* out          = (float*)d_out;

  const int B = in_sizes[0] / DIM;   // 128
  ansatz_kernel<<<B, BLK, 0, stream>>>(sre, sim, params, out);
}